// Round 10
// baseline (117.788 us; speedup 1.0000x reference)
//
#include <hip/hip_runtime.h>
#include <cmath>

#define WS  11
#define NX  160
#define NXY (NX*NX)
#define NB  2
#define TH  16
#define TW  32
#define MH  26              // mid rows = TH + 10
#define MST 36              // mid row stride
#define SST 48              // staged cols / LDS row stride (w0-8 .. w0+39)
#define DPB 5               // d-slices per block (NX/DPB = 32)
#define DCHUNK 40
#define PLANE_I 8192000     // NB*NX*NX*NX

struct GaussW { float g[WS]; };

// async global->LDS, 16B per lane; LDS dst is wave-uniform base + lane*16.
__device__ __forceinline__ void gload_lds16(const float* g, void* l) {
    __builtin_amdgcn_global_load_lds(
        (const __attribute__((address_space(1))) void*)g,
        (__attribute__((address_space(3))) void*)l, 16, 0, 0);
}

// k_whp: per block = 16x32 (h,w) tile streaming DPB d-slices. Per slice:
// issue async stage of slice s+1 into LDS buf^1 (global_load_lds, clamped
// addresses), W-blur slice s from LDS buf (5 fields on the fly, register
// window), barrier, H-blur from mid, store planar A[f], barrier, flip.
// Rationale: r6-r9 showed flat 93us at 50% occ with VALU 40% / HBM 39% --
// phases alternate pipes instead of overlapping; this keeps HBM loads in
// flight under compute. LDS 38.7KB -> 4 blocks/CU; hint (256,4) = proven
// spill-free budget (r7/r8: hints >=6 squeeze VGPR below 44 and spill).
__global__ __launch_bounds__(256, 4) void k_whp(const float* __restrict__ x,
                                                const float* __restrict__ y,
                                                float* __restrict__ A,
                                                GaussW gw) {
    __shared__ float sx[2][MH][SST];     // 2*4992 B
    __shared__ float sy[2][MH][SST];     // 2*4992 B
    __shared__ float mid[5][MH][MST];    // 18720 B

    const int tid = threadIdx.x;
    const int w0 = blockIdx.x * TW;
    const int h0 = blockIdx.y * TH;
    const int b  = blockIdx.z >> 5;            // NX/DPB = 32 chunks per batch
    const int d0 = (blockIdx.z & 31) * DPB;
    const int vol = b * (NX * NXY);

    // ---- staging address precompute: 312 16B-chunks = 26 rows x 12 quads ----
    // chunk ch -> r = ch/12, q = ch%12, staged [r][4q] <-> global (h0-5+r, w0-8+4q)
    // addresses clamped into the volume; out-of-range values are masked to zero
    // in the W-blur (cols) / rowok path (rows). NX%4==0 -> no partial chunks.
    const int r0s = tid / 12, q0s = tid % 12;
    const int a0g = vol + min(max(h0 - 5 + r0s, 0), NX - 1) * NX
                        + min(max(w0 - 8 + 4 * q0s, 0), NX - 4);
    const int ch1 = 256 + tid;                 // second pass: chunks 256..311
    const int r1s = ch1 / 12, q1s = ch1 % 12;
    const int a1g = vol + min(max(h0 - 5 + r1s, 0), NX - 1) * NX
                        + min(max(w0 - 8 + 4 * q1s, 0), NX - 4);
    const int wvoff = (tid >> 6) << 10;        // wave*1024 B into flat LDS tile

    // ---- W-blur role: 208 threads = 26 rows x 8 col-quads ----
    const int wr = tid >> 3;
    const int wq = tid & 7;
    const bool wbact = tid < 208;
    const bool rowok = (unsigned)(h0 - 5 + wr) < (unsigned)NX;
    const bool edgeblk = (w0 == 0) || (w0 == NX - TW);

    // ---- H-blur role: 160 threads = 5 fields x 4 row-groups x 8 col-quads ----
    const int hf  = tid >> 5;
    const int hr0 = ((tid >> 3) & 3) << 2;
    const int hq4 = (tid & 7) << 2;
    const bool hbact = tid < 160;
    const int obase0 = hf * PLANE_I + vol + (h0 + hr0) * NX + w0 + hq4;

    auto stage = [&](int buf, int d) {
        const int dof = d * NXY;
        gload_lds16(x + a0g + dof, (char*)&sx[buf][0][0] + wvoff);
        gload_lds16(y + a0g + dof, (char*)&sy[buf][0][0] + wvoff);
        if (tid < 56) {
            gload_lds16(x + a1g + dof, (char*)&sx[buf][0][0] + 4096);
            gload_lds16(y + a1g + dof, (char*)&sy[buf][0][0] + 4096);
        }
    };

    stage(0, d0);
    __syncthreads();                           // drains vmcnt -> sx[0] ready

    int cur = 0;
    for (int s = 0; s < DPB; ++s) {
        if (s + 1 < DPB) stage(cur ^ 1, d0 + s + 1);   // async, flies under phase 1

        // ---- Phase 1: W-blur from LDS ----
        if (wbact) {
            if (rowok) {
                float wx[20], wy[20];
                #pragma unroll
                for (int i = 0; i < 5; ++i) {
                    const float4 xv = *(const float4*)&sx[cur][wr][4 * wq + 4 * i];
                    const float4 yv = *(const float4*)&sy[cur][wr][4 * wq + 4 * i];
                    wx[4*i] = xv.x; wx[4*i+1] = xv.y; wx[4*i+2] = xv.z; wx[4*i+3] = xv.w;
                    wy[4*i] = yv.x; wy[4*i+1] = yv.y; wy[4*i+2] = yv.z; wy[4*i+3] = yv.w;
                }
                if (edgeblk) {                 // zero the out-of-volume staged cols
                    #pragma unroll
                    for (int m = 0; m < 20; ++m)
                        if ((unsigned)(w0 - 8 + 4 * wq + m) >= (unsigned)NX) {
                            wx[m] = 0.f; wy[m] = 0.f;
                        }
                }
                float a0[4] = {0,0,0,0}, a1[4] = {0,0,0,0}, a2[4] = {0,0,0,0},
                      a3[4] = {0,0,0,0}, a4[4] = {0,0,0,0};
                #pragma unroll
                for (int k = 0; k < WS; ++k) {
                    const float gk = gw.g[k];
                    #pragma unroll
                    for (int jj = 0; jj < 4; ++jj) {
                        const float xv = wx[3 + jj + k];
                        const float yv = wy[3 + jj + k];
                        const float t0 = gk * xv, t1 = gk * yv;
                        a0[jj] += t0;       a1[jj] += t1;
                        a2[jj] += t0 * xv;  a3[jj] += t1 * yv;  a4[jj] += t0 * yv;
                    }
                }
                *(float4*)&mid[0][wr][4*wq] = make_float4(a0[0], a0[1], a0[2], a0[3]);
                *(float4*)&mid[1][wr][4*wq] = make_float4(a1[0], a1[1], a1[2], a1[3]);
                *(float4*)&mid[2][wr][4*wq] = make_float4(a2[0], a2[1], a2[2], a2[3]);
                *(float4*)&mid[3][wr][4*wq] = make_float4(a3[0], a3[1], a3[2], a3[3]);
                *(float4*)&mid[4][wr][4*wq] = make_float4(a4[0], a4[1], a4[2], a4[3]);
            } else {
                const float4 z4 = make_float4(0.f, 0.f, 0.f, 0.f);
                *(float4*)&mid[0][wr][4*wq] = z4;
                *(float4*)&mid[1][wr][4*wq] = z4;
                *(float4*)&mid[2][wr][4*wq] = z4;
                *(float4*)&mid[3][wr][4*wq] = z4;
                *(float4*)&mid[4][wr][4*wq] = z4;
            }
        }
        __syncthreads();

        // ---- Phase 2: H-blur + store ----
        if (hbact) {
            float4 o0 = {0,0,0,0}, o1 = {0,0,0,0}, o2 = {0,0,0,0}, o3 = {0,0,0,0};
            #pragma unroll
            for (int k2 = 0; k2 < 14; ++k2) {
                const float4 v = *(const float4*)&mid[hf][hr0 + k2][hq4];
                if (k2 <= 10) { const float g = gw.g[k2];
                    o0.x += g*v.x; o0.y += g*v.y; o0.z += g*v.z; o0.w += g*v.w; }
                if (k2 >= 1 && k2 <= 11) { const float g = gw.g[k2-1];
                    o1.x += g*v.x; o1.y += g*v.y; o1.z += g*v.z; o1.w += g*v.w; }
                if (k2 >= 2 && k2 <= 12) { const float g = gw.g[k2-2];
                    o2.x += g*v.x; o2.y += g*v.y; o2.z += g*v.z; o2.w += g*v.w; }
                if (k2 >= 3) { const float g = gw.g[k2-3];
                    o3.x += g*v.x; o3.y += g*v.y; o3.z += g*v.z; o3.w += g*v.w; }
            }
            const int ob = obase0 + (d0 + s) * NXY;
            *(float4*)(A + ob)          = o0;
            *(float4*)(A + ob + NX)     = o1;
            *(float4*)(A + ob + 2*NX)   = o2;
            *(float4*)(A + ob + 3*NX)   = o3;
        }
        __syncthreads();
        cur ^= 1;
    }
}

// k_d: D-blur with register sliding window + SSIM + block reduce.
// (proven config: DCHUNK=40, 800 blocks, no outer unroll)
__global__ __launch_bounds__(256) void k_d(const float* __restrict__ A,
                                           float* __restrict__ partial,
                                           GaussW gw) {
    const int tid = threadIdx.x;
    const long long gidx = (long long)blockIdx.x * 256 + tid;
    const int NCOL = NB * NX * NX;
    const int chunk = (int)(gidx / NCOL);
    const int col   = (int)(gidx % NCOL);
    const int b  = col / (NX * NX);
    const int hw = col % (NX * NX);
    const int base = b * (NX * NXY) + hw;
    const int d0 = chunk * DCHUNK;

    float win[5][WS];
    #pragma unroll
    for (int i = 0; i < WS; ++i) {
        const int di = d0 - 5 + i;
        const bool ok = (di >= 0 && di < NX);
        const int o = base + (ok ? di : 0) * NXY;
        #pragma unroll
        for (int f = 0; f < 5; ++f)
            win[f][i] = ok ? A[f * PLANE_I + o] : 0.f;
    }

    float acc = 0.f;
    for (int dd = 0; dd < DCHUNK; ++dd) {
        float m[5];
        #pragma unroll
        for (int f = 0; f < 5; ++f) {
            float s = 0.f;
            #pragma unroll
            for (int i = 0; i < WS; ++i) s += gw.g[i] * win[f][i];
            m[f] = s;
        }
        const float mux = m[0], muy = m[1];
        const float mux2 = mux * mux, muy2 = muy * muy, muxy = mux * muy;
        const float sxx = m[2] - mux2, syy = m[3] - muy2, sxy = m[4] - muxy;
        const float num = (2.f * muxy + 1.0e-4f) * (2.f * sxy + 9.0e-4f);
        const float den = (mux2 + muy2 + 1.0e-4f) * (sxx + syy + 9.0e-4f);
        acc += num / den;

        const int dn = d0 + dd + 6;
        const bool ok = (dn < NX);
        const int o = base + (ok ? dn : 0) * NXY;
        #pragma unroll
        for (int f = 0; f < 5; ++f) {
            #pragma unroll
            for (int i = 0; i < WS - 1; ++i) win[f][i] = win[f][i + 1];
            win[f][WS - 1] = ok ? A[f * PLANE_I + o] : 0.f;
        }
    }

    for (int off = 32; off > 0; off >>= 1) acc += __shfl_down(acc, off, 64);
    __shared__ float wsum[4];
    if ((tid & 63) == 0) wsum[tid >> 6] = acc;
    __syncthreads();
    if (tid == 0) partial[blockIdx.x] = wsum[0] + wsum[1] + wsum[2] + wsum[3];
}

__global__ __launch_bounds__(256) void k_red(const float* __restrict__ partial,
                                             int n, float* __restrict__ out) {
    double s = 0.0;
    for (int i = threadIdx.x; i < n; i += 256) s += (double)partial[i];
    __shared__ double sd[256];
    sd[threadIdx.x] = s;
    __syncthreads();
    for (int st = 128; st > 0; st >>= 1) {
        if (threadIdx.x < st) sd[threadIdx.x] += sd[threadIdx.x + st];
        __syncthreads();
    }
    if (threadIdx.x == 0)
        out[0] = (float)(sd[0] / (double)((long long)NB * NX * NXY));
}

extern "C" void kernel_launch(void* const* d_in, const int* in_sizes, int n_in,
                              void* d_out, int out_size, void* d_ws, size_t ws_size,
                              hipStream_t stream) {
    const float* x = (const float*)d_in[0];
    const float* y = (const float*)d_in[1];
    float* A = (float*)d_ws;
    float* partial = (float*)((char*)d_ws + (size_t)5 * PLANE_I * sizeof(float));

    GaussW gw;
    {
        float tmp[WS]; float s = 0.f;
        for (int i = 0; i < WS; ++i) {
            const double e = exp(-(double)((i - 5) * (i - 5)) / 4.5);
            tmp[i] = (float)e; s += tmp[i];
        }
        for (int i = 0; i < WS; ++i) gw.g[i] = tmp[i] / s;
    }

    dim3 g1(NX / TW, NX / TH, NB * (NX / DPB));   // (5,10,64) = 3200 blocks
    k_whp<<<g1, 256, 0, stream>>>(x, y, A, gw);

    const int nblk2 = (NB * NX * NX * (NX / DCHUNK)) / 256;  // 800
    k_d<<<nblk2, 256, 0, stream>>>(A, partial, gw);

    k_red<<<1, 256, 0, stream>>>(partial, nblk2, (float*)d_out);
}